// Round 3
// baseline (89277.106 us; speedup 1.0000x reference)
//
#include <hip/hip_runtime.h>
#include <math.h>

// Problem dims (fixed)
#define T_SEQ 4096
#define DIN   64
#define DM    1024
#define G4    4096              // 4*DM gate rows
#define LSTRIDE_W ((size_t)G4 * DM)   // per-layer Wih/Whh stride
#define LSTRIDE_B ((size_t)G4)        // per-layer bias stride

typedef unsigned long long u64;
typedef unsigned int u32;

__device__ __forceinline__ float sigmoidf_(float x) {
    return 1.0f / (1.0f + __expf(-x));
}
__device__ __forceinline__ float tanhf_(float x) {
    float ax = fabsf(x);
    float e  = __expf(-2.0f * ax);
    float t  = (1.0f - e) / (1.0f + e);
    return copysignf(t, x);
}
__device__ __forceinline__ float lrelu_(float x) {
    return x > 0.0f ? x : 0.01f * x;
}
__device__ __forceinline__ float dot4_(float4 a, float4 b) {
    return a.x * b.x + a.y * b.y + a.z * b.z + a.w * b.w;
}

// ---------------------------------------------------------------------------
// K1: x[t,d] = leaky_relu(sum_k inp[t,k]*W1[d,k] + b1[d]);  grid=4096, block=256
// ---------------------------------------------------------------------------
__global__ __launch_bounds__(256) void k_input(const float* __restrict__ inp,
                                               const float* __restrict__ W1,
                                               const float* __restrict__ b1,
                                               float* __restrict__ x) {
    __shared__ float s_in[DIN];
    const int t   = blockIdx.x;
    const int tid = threadIdx.x;
    if (tid < DIN) s_in[tid] = inp[(size_t)t * DIN + tid];
    __syncthreads();
#pragma unroll
    for (int q = 0; q < 4; q++) {
        const int d = tid + q * 256;
        const float4* wr = (const float4*)(W1 + (size_t)d * DIN);
        float acc = 0.0f;
#pragma unroll
        for (int e = 0; e < 16; e++) {
            float4 w = wr[e];
            acc += w.x * s_in[e * 4 + 0] + w.y * s_in[e * 4 + 1] +
                   w.z * s_in[e * 4 + 2] + w.w * s_in[e * 4 + 3];
        }
        acc += b1[d];
        x[(size_t)t * DM + d] = lrelu_(acc);
    }
}

// ---------------------------------------------------------------------------
// K2: xg[m,n] = sum_k x[m,k]*Wih0[n,k] + (bih0[n]+bhh0[n])
// 128x128 tile, BK=16, 256 threads, 8x8 per thread.
// ---------------------------------------------------------------------------
__global__ __launch_bounds__(256) void k_gemm(const float* __restrict__ A,
                                              const float* __restrict__ B,
                                              const float* __restrict__ bih,
                                              const float* __restrict__ bhh,
                                              float* __restrict__ C) {
    const int K = DM;
    __shared__ float As[16][132];
    __shared__ float Bs[16][132];
    const int tid = threadIdx.x;
    const int m0 = blockIdx.y * 128, n0 = blockIdx.x * 128;
    const int tx = tid & 15, ty = tid >> 4;
    const int lr = tid >> 1;
    const int lc = (tid & 1) * 8;

    float acc[8][8] = {};
    const float4* ag = (const float4*)(A + (size_t)(m0 + lr) * K + lc);
    const float4* bg = (const float4*)(B + (size_t)(n0 + lr) * K + lc);

    for (int k0 = 0; k0 < K; k0 += 16) {
        float4 a0 = ag[0], a1 = ag[1];
        float4 b0 = bg[0], b1v = bg[1];
        ag += 4; bg += 4;
        __syncthreads();
        As[lc + 0][lr] = a0.x; As[lc + 1][lr] = a0.y; As[lc + 2][lr] = a0.z; As[lc + 3][lr] = a0.w;
        As[lc + 4][lr] = a1.x; As[lc + 5][lr] = a1.y; As[lc + 6][lr] = a1.z; As[lc + 7][lr] = a1.w;
        Bs[lc + 0][lr] = b0.x; Bs[lc + 1][lr] = b0.y; Bs[lc + 2][lr] = b0.z; Bs[lc + 3][lr] = b0.w;
        Bs[lc + 4][lr] = b1v.x; Bs[lc + 5][lr] = b1v.y; Bs[lc + 6][lr] = b1v.z; Bs[lc + 7][lr] = b1v.w;
        __syncthreads();
#pragma unroll
        for (int k = 0; k < 16; k++) {
            float a[8], b[8];
            *(float4*)&a[0] = *(const float4*)&As[k][ty * 8 + 0];
            *(float4*)&a[4] = *(const float4*)&As[k][ty * 8 + 4];
            *(float4*)&b[0] = *(const float4*)&Bs[k][tx * 8 + 0];
            *(float4*)&b[4] = *(const float4*)&Bs[k][tx * 8 + 4];
#pragma unroll
            for (int i = 0; i < 8; i++)
#pragma unroll
                for (int j = 0; j < 8; j++)
                    acc[i][j] += a[i] * b[j];
        }
    }
    float bj[8];
#pragma unroll
    for (int j = 0; j < 8; j++) {
        int n = n0 + tx * 8 + j;
        bj[j] = bih[n] + bhh[n];
    }
#pragma unroll
    for (int i = 0; i < 8; i++) {
        float4 v0, v1;
        v0.x = acc[i][0] + bj[0]; v0.y = acc[i][1] + bj[1];
        v0.z = acc[i][2] + bj[2]; v0.w = acc[i][3] + bj[3];
        v1.x = acc[i][4] + bj[4]; v1.y = acc[i][5] + bj[5];
        v1.z = acc[i][6] + bj[6]; v1.w = acc[i][7] + bj[7];
        float* cp = C + (size_t)(m0 + ty * 8 + i) * G4 + n0 + tx * 8;
        *(float4*)(cp + 0) = v0;
        *(float4*)(cp + 4) = v1;
    }
}

// ---------------------------------------------------------------------------
// K3: fused 2-layer pipelined scan. grid=256 WGs x 256 threads, 1 WG/CU.
// Round t (t=0..T): computes h0[t] (layer 0) and h1[t-1] (layer 1).
// WG w owns h-indices [4w,4w+4) for both layers.
// Thread (rg=tid>>5, ck=tid&31): 2 rows from each of 3 GEMV groups
//   G0 = Whh0 rows (dot h0_prev), G1 = Wih1 rows (dot h0_prev),
//   G2 = Whh1 rows (dot h1_prev), k-chunk [ck*32, ck*32+32). 192 weight VGPRs.
// Exchange: value+tag packed in u64 slots (relaxed agent atomics, parity
// double-buffer); readiness via 8 shared per-round counters (one 64B line ->
// coalesced polling), release-fetch_add once per WG.
// ---------------------------------------------------------------------------
__global__ __launch_bounds__(256, 1) void k_scan2(
        const float* __restrict__ xg,     // T x 4096 (layer-0 input preacts)
        const float* __restrict__ Wih1,   // layer-1 input weights 4096x1024
        const float* __restrict__ Whh0,   // layer-0 recurrent 4096x1024
        const float* __restrict__ Whh1,   // layer-1 recurrent 4096x1024
        const float* __restrict__ bih1,
        const float* __restrict__ bhh1,
        u64* sl0,                         // [2][1024] packed h0 slots
        u64* sl1,                         // [2][1024] packed h1 slots
        u32* ctr,                         // [(T+2)][8] round counters (zeroed)
        float* __restrict__ out) {
    const int tid = threadIdx.x;
    const int w   = blockIdx.x;
    const int rg  = tid >> 5;             // 0..7 row-group
    const int ck  = tid & 31;             // 0..31 k-chunk

    __shared__ float hl0[32 * 36];        // h0_prev staged, chunk stride 36
    __shared__ float hl1[32 * 36];        // h1_prev staged
    __shared__ float gp0[16], gp1[16], gp2[16];

    // ---- weight prologue: 6 rows x 32 k in registers ----
    float4 wr0[2][8], wr1[2][8], wr2[2][8];
#pragma unroll
    for (int q = 0; q < 2; q++) {
        const int row = rg * 2 + q;                 // 0..15
        const int g = row >> 2, s = row & 3;
        const size_t rbase = (size_t)(g * DM + w * 4 + s) * DM + ck * 32;
        const float4* p0 = (const float4*)(Whh0 + rbase);
        const float4* p1 = (const float4*)(Wih1 + rbase);
        const float4* p2 = (const float4*)(Whh1 + rbase);
#pragma unroll
        for (int e = 0; e < 8; e++) {
            wr0[q][e] = p0[e]; wr1[q][e] = p1[e]; wr2[q][e] = p2[e];
        }
    }
    // layer-1 bias (state threads 4..7)
    float b1s[4] = {0.f, 0.f, 0.f, 0.f};
    if (tid >= 4 && tid < 8) {
        const int s = tid - 4;
#pragma unroll
        for (int g = 0; g < 4; g++)
            b1s[g] = bih1[g * DM + w * 4 + s] + bhh1[g * DM + w * 4 + s];
    }

    const int stc = tid >> 3;             // stage chunk 0..31
    const int sto = (tid & 7) * 4;        // offset within chunk
    float c0 = 0.f, h0 = 0.f, c1 = 0.f, h1 = 0.f;

    for (int t = 0; t <= T_SEQ; t++) {
        // prefetch layer-0 input preacts for this round (state threads)
        float xgv0 = 0.f, xgv1 = 0.f, xgv2 = 0.f, xgv3 = 0.f;
        if (tid < 4 && t < T_SEQ) {
            const float* xp = xg + (size_t)t * G4 + w * 4 + tid;
            xgv0 = xp[0]; xgv1 = xp[DM]; xgv2 = xp[2 * DM]; xgv3 = xp[3 * DM];
        }

        if (t == 0) {
            float4 z; z.x = z.y = z.z = z.w = 0.f;
            *(float4*)&hl0[stc * 36 + sto] = z;
            *(float4*)&hl1[stc * 36 + sto] = z;
        } else {
            // 1) cheap coalesced readiness poll: 8 counters in one 64B line
            const u32* cp = &ctr[(size_t)t * 8 + (tid & 7)];
            while (__hip_atomic_load(cp, __ATOMIC_RELAXED,
                                     __HIP_MEMORY_SCOPE_AGENT) != 32u) { }
            // 2) payload: tag-validated packed slots (usually 1 iteration)
            const int par = t & 1;
            const u64* p0 = sl0 + (size_t)par * 1024 + tid * 4;
            const u64* p1 = sl1 + (size_t)par * 1024 + tid * 4;
            const u32 want = (u32)t;
            u64 a0, a1, a2, a3, d0, d1, d2, d3;
            for (;;) {
                a0 = __hip_atomic_load(p0 + 0, __ATOMIC_RELAXED, __HIP_MEMORY_SCOPE_AGENT);
                a1 = __hip_atomic_load(p0 + 1, __ATOMIC_RELAXED, __HIP_MEMORY_SCOPE_AGENT);
                a2 = __hip_atomic_load(p0 + 2, __ATOMIC_RELAXED, __HIP_MEMORY_SCOPE_AGENT);
                a3 = __hip_atomic_load(p0 + 3, __ATOMIC_RELAXED, __HIP_MEMORY_SCOPE_AGENT);
                d0 = __hip_atomic_load(p1 + 0, __ATOMIC_RELAXED, __HIP_MEMORY_SCOPE_AGENT);
                d1 = __hip_atomic_load(p1 + 1, __ATOMIC_RELAXED, __HIP_MEMORY_SCOPE_AGENT);
                d2 = __hip_atomic_load(p1 + 2, __ATOMIC_RELAXED, __HIP_MEMORY_SCOPE_AGENT);
                d3 = __hip_atomic_load(p1 + 3, __ATOMIC_RELAXED, __HIP_MEMORY_SCOPE_AGENT);
                bool ok = ((u32)(a0 >> 32) == want) & ((u32)(a1 >> 32) == want) &
                          ((u32)(a2 >> 32) == want) & ((u32)(a3 >> 32) == want) &
                          ((u32)(d0 >> 32) == want) & ((u32)(d1 >> 32) == want) &
                          ((u32)(d2 >> 32) == want) & ((u32)(d3 >> 32) == want);
                if (ok) break;
            }
            float4 hv0, hv1;
            hv0.x = __uint_as_float((u32)a0); hv0.y = __uint_as_float((u32)a1);
            hv0.z = __uint_as_float((u32)a2); hv0.w = __uint_as_float((u32)a3);
            hv1.x = __uint_as_float((u32)d0); hv1.y = __uint_as_float((u32)d1);
            hv1.z = __uint_as_float((u32)d2); hv1.w = __uint_as_float((u32)d3);
            *(float4*)&hl0[stc * 36 + sto] = hv0;
            *(float4*)&hl1[stc * 36 + sto] = hv1;
        }
        __syncthreads();

        // ---- three GEMV groups: 6 dots of width 32 ----
        float s00 = 0.f, s01 = 0.f, s10 = 0.f, s11 = 0.f, s20 = 0.f, s21 = 0.f;
        {
            const float* hp0 = &hl0[ck * 36];
            const float* hp1 = &hl1[ck * 36];
#pragma unroll
            for (int e = 0; e < 8; e++) {
                float4 h0v = *(const float4*)&hp0[e * 4];
                float4 h1v = *(const float4*)&hp1[e * 4];
                s00 += dot4_(wr0[0][e], h0v);
                s01 += dot4_(wr0[1][e], h0v);
                s10 += dot4_(wr1[0][e], h0v);
                s11 += dot4_(wr1[1][e], h0v);
                s20 += dot4_(wr2[0][e], h1v);
                s21 += dot4_(wr2[1][e], h1v);
            }
        }
#pragma unroll
        for (int m = 1; m <= 16; m <<= 1) {
            s00 += __shfl_xor(s00, m, 64);
            s01 += __shfl_xor(s01, m, 64);
            s10 += __shfl_xor(s10, m, 64);
            s11 += __shfl_xor(s11, m, 64);
            s20 += __shfl_xor(s20, m, 64);
            s21 += __shfl_xor(s21, m, 64);
        }
        if (ck == 0) {
            gp0[rg * 2 + 0] = s00; gp0[rg * 2 + 1] = s01;
            gp1[rg * 2 + 0] = s10; gp1[rg * 2 + 1] = s11;
            gp2[rg * 2 + 0] = s20; gp2[rg * 2 + 1] = s21;
        }
        __syncthreads();

        // ---- gate math + publish (wave 0 only; program order guarantees
        //      all 8 slot stores precede tid 0's release fetch_add) ----
        if (tid < 4) {
            const int s = tid;
            float pi = xgv0 + gp0[0 + s];
            float pf = xgv1 + gp0[4 + s];
            float pg = xgv2 + gp0[8 + s];
            float po = xgv3 + gp0[12 + s];
            c0 = sigmoidf_(pf) * c0 + sigmoidf_(pi) * tanhf_(pg);
            h0 = sigmoidf_(po) * tanhf_(c0);
            u64 v = ((u64)(u32)(t + 1) << 32) | (u64)__float_as_uint(h0);
            __hip_atomic_store(sl0 + (size_t)((t + 1) & 1) * 1024 + w * 4 + s, v,
                               __ATOMIC_RELAXED, __HIP_MEMORY_SCOPE_AGENT);
        } else if (tid < 8) {
            const int s = tid - 4;
            if (t > 0) {
                float pi = gp1[0 + s]  + gp2[0 + s]  + b1s[0];
                float pf = gp1[4 + s]  + gp2[4 + s]  + b1s[1];
                float pg = gp1[8 + s]  + gp2[8 + s]  + b1s[2];
                float po = gp1[12 + s] + gp2[12 + s] + b1s[3];
                c1 = sigmoidf_(pf) * c1 + sigmoidf_(pi) * tanhf_(pg);
                h1 = sigmoidf_(po) * tanhf_(c1);
            }
            u64 v = ((u64)(u32)(t + 1) << 32) | (u64)__float_as_uint(h1);
            __hip_atomic_store(sl1 + (size_t)((t + 1) & 1) * 1024 + w * 4 + s, v,
                               __ATOMIC_RELAXED, __HIP_MEMORY_SCOPE_AGENT);
        }
        if (tid == 0) {
            __hip_atomic_fetch_add(&ctr[(size_t)(t + 1) * 8 + (w >> 5)], 1u,
                                   __ATOMIC_RELEASE, __HIP_MEMORY_SCOPE_AGENT);
        }
        // no 3rd barrier needed: next round's hl writes don't touch gp, and
        // next round's gp writes are behind the next staging barrier.
    }

    if (tid >= 4 && tid < 8) {
        out[w * 4 + (tid - 4)] = lrelu_(h1);
    }
}

// ---------------------------------------------------------------------------
extern "C" void kernel_launch(void* const* d_in, const int* in_sizes, int n_in,
                              void* d_out, int out_size, void* d_ws, size_t ws_size,
                              hipStream_t stream) {
    const float* inp = (const float*)d_in[0];   // 4096 x 64
    const float* W1  = (const float*)d_in[1];   // 1024 x 64
    const float* b1  = (const float*)d_in[2];   // 1024
    const float* Wih = (const float*)d_in[3];   // 2 x 4096 x 1024
    const float* Whh = (const float*)d_in[4];   // 2 x 4096 x 1024
    const float* bih = (const float*)d_in[5];   // 2 x 4096
    const float* bhh = (const float*)d_in[6];   // 2 x 4096
    float* out = (float*)d_out;                 // 1024

    // workspace layout
    float* x   = (float*)d_ws;                          // 4096*1024 f
    float* xg  = x + (size_t)T_SEQ * DM;                // 4096*4096 f
    u64*   sl0 = (u64*)(xg + (size_t)T_SEQ * G4);       // 2*1024 u64
    u64*   sl1 = sl0 + 2048;                            // 2*1024 u64
    u32*   ctr = (u32*)(sl1 + 2048);                    // (T+2)*8 u32
    (void)in_sizes; (void)n_in; (void)out_size; (void)ws_size;

    // zero the round counters (graph-capture-legal)
    hipMemsetAsync(ctr, 0, (size_t)(T_SEQ + 2) * 8 * sizeof(u32), stream);

    // Phase 1: input projection
    k_input<<<dim3(T_SEQ), dim3(256), 0, stream>>>(inp, W1, b1, x);

    // Phase 2: xg = x @ Wih0^T + (bih0+bhh0)
    k_gemm<<<dim3(32, 32), dim3(256), 0, stream>>>(x, Wih, bih, bhh, xg);

    // Phase 3: fused 2-layer pipelined scan
    k_scan2<<<dim3(256), dim3(256), 0, stream>>>(
        xg, Wih + LSTRIDE_W, Whh, Whh + LSTRIDE_W,
        bih + LSTRIDE_B, bhh + LSTRIDE_B, sl0, sl1, ctr, out);
}

// Round 4
// 59564.246 us; speedup vs baseline: 1.4988x; 1.4988x over previous
//
#include <hip/hip_runtime.h>
#include <math.h>

// Problem dims (fixed)
#define T_SEQ 4096
#define DIN   64
#define DM    1024
#define G4    4096              // 4*DM gate rows
#define LSTRIDE_W ((size_t)G4 * DM)   // per-layer Wih/Whh stride
#define LSTRIDE_B ((size_t)G4)        // per-layer bias stride

typedef unsigned int u32;

__device__ __forceinline__ float sigmoidf_(float x) {
    return 1.0f / (1.0f + __expf(-x));
}
__device__ __forceinline__ float tanhf_(float x) {
    float ax = fabsf(x);
    float e  = __expf(-2.0f * ax);
    float t  = (1.0f - e) / (1.0f + e);
    return copysignf(t, x);
}
__device__ __forceinline__ float lrelu_(float x) {
    return x > 0.0f ? x : 0.01f * x;
}
__device__ __forceinline__ float dot4_(float4 a, float4 b) {
    return a.x * b.x + a.y * b.y + a.z * b.z + a.w * b.w;
}

// ---------------------------------------------------------------------------
// K1: x[t,d] = leaky_relu(sum_k inp[t,k]*W1[d,k] + b1[d]);  grid=4096, block=256
// ---------------------------------------------------------------------------
__global__ __launch_bounds__(256) void k_input(const float* __restrict__ inp,
                                               const float* __restrict__ W1,
                                               const float* __restrict__ b1,
                                               float* __restrict__ x) {
    __shared__ float s_in[DIN];
    const int t   = blockIdx.x;
    const int tid = threadIdx.x;
    if (tid < DIN) s_in[tid] = inp[(size_t)t * DIN + tid];
    __syncthreads();
#pragma unroll
    for (int q = 0; q < 4; q++) {
        const int d = tid + q * 256;
        const float4* wr = (const float4*)(W1 + (size_t)d * DIN);
        float acc = 0.0f;
#pragma unroll
        for (int e = 0; e < 16; e++) {
            float4 w = wr[e];
            acc += w.x * s_in[e * 4 + 0] + w.y * s_in[e * 4 + 1] +
                   w.z * s_in[e * 4 + 2] + w.w * s_in[e * 4 + 3];
        }
        acc += b1[d];
        x[(size_t)t * DM + d] = lrelu_(acc);
    }
}

// ---------------------------------------------------------------------------
// K2/K4: C[m,n] = sum_k A[m,k]*B[n,k] + (bih[n]+bhh[n])
// 128x128 tile, BK=16, 256 threads, 8x8 per thread.
// ---------------------------------------------------------------------------
__global__ __launch_bounds__(256) void k_gemm(const float* __restrict__ A,
                                              const float* __restrict__ B,
                                              const float* __restrict__ bih,
                                              const float* __restrict__ bhh,
                                              float* __restrict__ C) {
    const int K = DM;
    __shared__ float As[16][132];
    __shared__ float Bs[16][132];
    const int tid = threadIdx.x;
    const int m0 = blockIdx.y * 128, n0 = blockIdx.x * 128;
    const int tx = tid & 15, ty = tid >> 4;
    const int lr = tid >> 1;
    const int lc = (tid & 1) * 8;

    float acc[8][8] = {};
    const float4* ag = (const float4*)(A + (size_t)(m0 + lr) * K + lc);
    const float4* bg = (const float4*)(B + (size_t)(n0 + lr) * K + lc);

    for (int k0 = 0; k0 < K; k0 += 16) {
        float4 a0 = ag[0], a1 = ag[1];
        float4 b0 = bg[0], b1v = bg[1];
        ag += 4; bg += 4;
        __syncthreads();
        As[lc + 0][lr] = a0.x; As[lc + 1][lr] = a0.y; As[lc + 2][lr] = a0.z; As[lc + 3][lr] = a0.w;
        As[lc + 4][lr] = a1.x; As[lc + 5][lr] = a1.y; As[lc + 6][lr] = a1.z; As[lc + 7][lr] = a1.w;
        Bs[lc + 0][lr] = b0.x; Bs[lc + 1][lr] = b0.y; Bs[lc + 2][lr] = b0.z; Bs[lc + 3][lr] = b0.w;
        Bs[lc + 4][lr] = b1v.x; Bs[lc + 5][lr] = b1v.y; Bs[lc + 6][lr] = b1v.z; Bs[lc + 7][lr] = b1v.w;
        __syncthreads();
#pragma unroll
        for (int k = 0; k < 16; k++) {
            float a[8], b[8];
            *(float4*)&a[0] = *(const float4*)&As[k][ty * 8 + 0];
            *(float4*)&a[4] = *(const float4*)&As[k][ty * 8 + 4];
            *(float4*)&b[0] = *(const float4*)&Bs[k][tx * 8 + 0];
            *(float4*)&b[4] = *(const float4*)&Bs[k][tx * 8 + 4];
#pragma unroll
            for (int i = 0; i < 8; i++)
#pragma unroll
                for (int j = 0; j < 8; j++)
                    acc[i][j] += a[i] * b[j];
        }
    }
    float bj[8];
#pragma unroll
    for (int j = 0; j < 8; j++) {
        int n = n0 + tx * 8 + j;
        bj[j] = bih[n] + bhh[n];
    }
#pragma unroll
    for (int i = 0; i < 8; i++) {
        float4 v0, v1;
        v0.x = acc[i][0] + bj[0]; v0.y = acc[i][1] + bj[1];
        v0.z = acc[i][2] + bj[2]; v0.w = acc[i][3] + bj[3];
        v1.x = acc[i][4] + bj[4]; v1.y = acc[i][5] + bj[5];
        v1.z = acc[i][6] + bj[6]; v1.w = acc[i][7] + bj[7];
        float* cp = C + (size_t)(m0 + ty * 8 + i) * G4 + n0 + tx * 8;
        *(float4*)(cp + 0) = v0;
        *(float4*)(cp + 4) = v1;
    }
}

// ---------------------------------------------------------------------------
// K3/K5: sequential LSTM scan. grid=256 WGs x 256 threads, 1 WG/CU.
// WG w owns h-indices [4w,4w+4) -> 16 gate rows {g*1024 + 4w + s}.
// R4 changes vs R2:
//  * Weights live in LDS (64 KB/WG), loaded once in the prologue. Layout is
//    lane-contiguous per wave per k-step -> ds_read_b128 conflict-free.
//    (Compiler refuses to hoist >~48 weight VGPRs across the scan loop; LDS
//    self-storage is the deterministic fix for the 400+ GB re-fetch seen in
//    R2/R3 FETCH_SIZE.)
//  * Readiness: 8 per-round counters in ONE 64B line; producers do one
//    release fetch_add per WG; consumers spin with threads 0..7 only.
//  * Payload: fp32 slots (parity double-buffer), relaxed agent 4B atomic
//    loads (cache-bypassing). Release ordering makes them valid; no tags.
// ---------------------------------------------------------------------------
__global__ __launch_bounds__(256, 1) void k_scan(const float* __restrict__ xg,
                                                 const float* __restrict__ Whh,
                                                 float* __restrict__ hbuf,
                                                 u32* slots,   // [2][1024]
                                                 u32* ctr,     // [(T+1)][8]
                                                 float* __restrict__ out) {
    const int tid = threadIdx.x;
    const int w   = blockIdx.x;
    const int wv  = tid >> 6;             // wave 0..3
    const int ln  = tid & 63;             // lane
    const int rs  = tid >> 4;             // row 0..15 (g = rs>>2, s = rs&3)
    const int ck  = tid & 15;             // k-chunk of 64
    const int g   = rs >> 2, s = rs & 3;
    const int r   = g * DM + w * 4 + s;   // global gate row

    __shared__ float wlds[4 * 4096];      // 64 KB weights, [wave][e][lane*4]
    __shared__ float hl[16 * 68];         // h staged, chunk stride 68
    __shared__ float gp[16];              // gate preactivations

    // ---- prologue: weights -> LDS (self-storage; each thread reads back
    //      exactly what it wrote, lane-contiguous => conflict-free) ----
    {
        const float4* gw = (const float4*)(Whh + (size_t)r * DM + ck * 64);
#pragma unroll
        for (int e = 0; e < 16; e++) {
            float4 v = gw[e];
            *(float4*)&wlds[wv * 4096 + e * 256 + ln * 4] = v;
        }
    }
    __syncthreads();

    const int stc = tid >> 4;             // stage chunk for h[tid*4..+4)
    const int sto = (tid & 15) * 4;
    float c_state = 0.0f, h_last = 0.0f;

    for (int t = 0; t < T_SEQ; t++) {
        // prefetch this round's input preactivation (one per gate row)
        float xgv = 0.0f;
        if (ck == 0) xgv = xg[(size_t)t * G4 + r];

        if (t == 0) {
            float4 z; z.x = z.y = z.z = z.w = 0.0f;
            *(float4*)&hl[stc * 68 + sto] = z;
        } else {
            // 1) readiness: threads 0..7 spin on 8 counters (one 64B line)
            if (tid < 8) {
                const u32* cp = &ctr[(size_t)t * 8 + tid];
                while (__hip_atomic_load(cp, __ATOMIC_RELAXED,
                                         __HIP_MEMORY_SCOPE_AGENT) != 32u) { }
            }
            __syncthreads();
            // 2) payload: cache-bypassing loads of h[t] (parity buffer)
            const u32* sp = slots + (size_t)(t & 1) * 1024 + tid * 4;
            u32 b0 = __hip_atomic_load(sp + 0, __ATOMIC_RELAXED, __HIP_MEMORY_SCOPE_AGENT);
            u32 b1 = __hip_atomic_load(sp + 1, __ATOMIC_RELAXED, __HIP_MEMORY_SCOPE_AGENT);
            u32 b2 = __hip_atomic_load(sp + 2, __ATOMIC_RELAXED, __HIP_MEMORY_SCOPE_AGENT);
            u32 b3 = __hip_atomic_load(sp + 3, __ATOMIC_RELAXED, __HIP_MEMORY_SCOPE_AGENT);
            float4 hv;
            hv.x = __uint_as_float(b0); hv.y = __uint_as_float(b1);
            hv.z = __uint_as_float(b2); hv.w = __uint_as_float(b3);
            *(float4*)&hl[stc * 68 + sto] = hv;
        }
        __syncthreads();

        // ---- dot: row r, k-chunk [ck*64, +64), weights from LDS ----
        const float* wp = &wlds[wv * 4096 + ln * 4];
        const float* hp = &hl[ck * 68];
        float a0 = 0.f, a1 = 0.f, a2 = 0.f, a3 = 0.f;
#pragma unroll
        for (int e = 0; e < 16; e++) {
            float4 wv4 = *(const float4*)&wp[e * 256];
            float4 hv4 = *(const float4*)&hp[e * 4];
            a0 += wv4.x * hv4.x;
            a1 += wv4.y * hv4.y;
            a2 += wv4.z * hv4.z;
            a3 += wv4.w * hv4.w;
        }
        float acc = (a0 + a1) + (a2 + a3);
        acc += __shfl_xor(acc, 1, 16);
        acc += __shfl_xor(acc, 2, 16);
        acc += __shfl_xor(acc, 4, 16);
        acc += __shfl_xor(acc, 8, 16);
        if (ck == 0) gp[rs] = xgv + acc;
        __syncthreads();

        // ---- gate math + publish (wave 0; program order puts the 4 slot
        //      stores before tid 0's release fetch_add) ----
        if (tid < 4) {
            float i_ = gp[0 + tid];
            float f_ = gp[4 + tid];
            float g_ = gp[8 + tid];
            float o_ = gp[12 + tid];
            c_state = sigmoidf_(f_) * c_state + sigmoidf_(i_) * tanhf_(g_);
            float h = sigmoidf_(o_) * tanhf_(c_state);
            h_last = h;
            hbuf[(size_t)(t + 1) * DM + w * 4 + tid] = h;   // history (for GEMM)
            __hip_atomic_store(slots + (size_t)((t + 1) & 1) * 1024 + w * 4 + tid,
                               __float_as_uint(h),
                               __ATOMIC_RELAXED, __HIP_MEMORY_SCOPE_AGENT);
        }
        if (tid == 0) {
            __hip_atomic_fetch_add(&ctr[(size_t)(t + 1) * 8 + (w >> 5)], 1u,
                                   __ATOMIC_RELEASE, __HIP_MEMORY_SCOPE_AGENT);
        }
        // no extra barrier: next round's hl writes are behind the staging
        // barrier; gp reads of this round finish before tid<4 reach it.
    }

    if (out != nullptr && tid < 4) {
        out[w * 4 + tid] = lrelu_(h_last);
    }
}

// ---------------------------------------------------------------------------
extern "C" void kernel_launch(void* const* d_in, const int* in_sizes, int n_in,
                              void* d_out, int out_size, void* d_ws, size_t ws_size,
                              hipStream_t stream) {
    const float* inp = (const float*)d_in[0];   // 4096 x 64
    const float* W1  = (const float*)d_in[1];   // 1024 x 64
    const float* b1  = (const float*)d_in[2];   // 1024
    const float* Wih = (const float*)d_in[3];   // 2 x 4096 x 1024
    const float* Whh = (const float*)d_in[4];   // 2 x 4096 x 1024
    const float* bih = (const float*)d_in[5];   // 2 x 4096
    const float* bhh = (const float*)d_in[6];   // 2 x 4096
    float* out = (float*)d_out;                 // 1024

    // workspace layout (fp32 elements unless noted)
    float* x   = (float*)d_ws;                          // 4096*1024
    float* xg  = x + (size_t)T_SEQ * DM;                // 4096*4096
    float* hb1 = xg + (size_t)T_SEQ * G4;               // 4097*1024
    float* hb2 = hb1 + (size_t)(T_SEQ + 1) * DM;        // 4097*1024
    u32*   sl0 = (u32*)(hb2 + (size_t)(T_SEQ + 1) * DM);   // 2*1024
    u32*   sl1 = sl0 + 2048;                               // 2*1024
    u32*   ct0 = sl1 + 2048;                               // (T+1)*8
    u32*   ct1 = ct0 + (size_t)(T_SEQ + 1) * 8;            // (T+1)*8
    (void)in_sizes; (void)n_in; (void)out_size; (void)ws_size;

    // zero both counter arrays (contiguous; graph-capture-legal)
    hipMemsetAsync(ct0, 0, (size_t)2 * (T_SEQ + 1) * 8 * sizeof(u32), stream);

    // Phase 1: input projection
    k_input<<<dim3(T_SEQ), dim3(256), 0, stream>>>(inp, W1, b1, x);

    // Phase 2: xg = x @ Wih0^T + (bih0+bhh0)
    k_gemm<<<dim3(32, 32), dim3(256), 0, stream>>>(x, Wih, bih, bhh, xg);

    // Phase 3: layer-0 scan (writes hb1[1..T])
    k_scan<<<dim3(256), dim3(256), 0, stream>>>(xg, Whh, hb1, sl0, ct0, nullptr);

    // Phase 4: xg = hs1 @ Wih1^T + (bih1+bhh1)
    k_gemm<<<dim3(32, 32), dim3(256), 0, stream>>>(hb1 + DM, Wih + LSTRIDE_W,
                                                   bih + LSTRIDE_B, bhh + LSTRIDE_B, xg);

    // Phase 5: layer-1 scan, final h -> leaky_relu -> out
    k_scan<<<dim3(256), dim3(256), 0, stream>>>(xg, Whh + LSTRIDE_W, hb2, sl1, ct1, out);
}

// Round 5
// 27748.895 us; speedup vs baseline: 3.2173x; 2.1465x over previous
//
#include <hip/hip_runtime.h>
#include <math.h>

// Problem dims (fixed)
#define T_SEQ 4096
#define DIN   64
#define DM    1024
#define G4    4096              // 4*DM gate rows
#define LSTRIDE_W ((size_t)G4 * DM)   // per-layer Wih/Whh stride
#define LSTRIDE_B ((size_t)G4)        // per-layer bias stride

typedef unsigned long long u64;
typedef unsigned int u32;

__device__ __forceinline__ float sigmoidf_(float x) {
    return 1.0f / (1.0f + __expf(-x));
}
__device__ __forceinline__ float tanhf_(float x) {
    float ax = fabsf(x);
    float e  = __expf(-2.0f * ax);
    float t  = (1.0f - e) / (1.0f + e);
    return copysignf(t, x);
}
__device__ __forceinline__ float lrelu_(float x) {
    return x > 0.0f ? x : 0.01f * x;
}

// ---------------------------------------------------------------------------
// K1: x[t,d] = leaky_relu(sum_k inp[t,k]*W1[d,k] + b1[d]);  grid=4096, block=256
// ---------------------------------------------------------------------------
__global__ __launch_bounds__(256) void k_input(const float* __restrict__ inp,
                                               const float* __restrict__ W1,
                                               const float* __restrict__ b1,
                                               float* __restrict__ x) {
    __shared__ float s_in[DIN];
    const int t   = blockIdx.x;
    const int tid = threadIdx.x;
    if (tid < DIN) s_in[tid] = inp[(size_t)t * DIN + tid];
    __syncthreads();
#pragma unroll
    for (int q = 0; q < 4; q++) {
        const int d = tid + q * 256;
        const float4* wr = (const float4*)(W1 + (size_t)d * DIN);
        float acc = 0.0f;
#pragma unroll
        for (int e = 0; e < 16; e++) {
            float4 w = wr[e];
            acc += w.x * s_in[e * 4 + 0] + w.y * s_in[e * 4 + 1] +
                   w.z * s_in[e * 4 + 2] + w.w * s_in[e * 4 + 3];
        }
        acc += b1[d];
        x[(size_t)t * DM + d] = lrelu_(acc);
    }
}

// ---------------------------------------------------------------------------
// K2/K4: C[m,n] = sum_k A[m,k]*B[n,k] + (bih[n]+bhh[n])
// 128x128 tile, BK=16, 256 threads, 8x8 per thread.
// ---------------------------------------------------------------------------
__global__ __launch_bounds__(256) void k_gemm(const float* __restrict__ A,
                                              const float* __restrict__ B,
                                              const float* __restrict__ bih,
                                              const float* __restrict__ bhh,
                                              float* __restrict__ C) {
    const int K = DM;
    __shared__ float As[16][132];
    __shared__ float Bs[16][132];
    const int tid = threadIdx.x;
    const int m0 = blockIdx.y * 128, n0 = blockIdx.x * 128;
    const int tx = tid & 15, ty = tid >> 4;
    const int lr = tid >> 1;
    const int lc = (tid & 1) * 8;

    float acc[8][8] = {};
    const float4* ag = (const float4*)(A + (size_t)(m0 + lr) * K + lc);
    const float4* bg = (const float4*)(B + (size_t)(n0 + lr) * K + lc);

    for (int k0 = 0; k0 < K; k0 += 16) {
        float4 a0 = ag[0], a1 = ag[1];
        float4 b0 = bg[0], b1v = bg[1];
        ag += 4; bg += 4;
        __syncthreads();
        As[lc + 0][lr] = a0.x; As[lc + 1][lr] = a0.y; As[lc + 2][lr] = a0.z; As[lc + 3][lr] = a0.w;
        As[lc + 4][lr] = a1.x; As[lc + 5][lr] = a1.y; As[lc + 6][lr] = a1.z; As[lc + 7][lr] = a1.w;
        Bs[lc + 0][lr] = b0.x; Bs[lc + 1][lr] = b0.y; Bs[lc + 2][lr] = b0.z; Bs[lc + 3][lr] = b0.w;
        Bs[lc + 4][lr] = b1v.x; Bs[lc + 5][lr] = b1v.y; Bs[lc + 6][lr] = b1v.z; Bs[lc + 7][lr] = b1v.w;
        __syncthreads();
#pragma unroll
        for (int k = 0; k < 16; k++) {
            float a[8], b[8];
            *(float4*)&a[0] = *(const float4*)&As[k][ty * 8 + 0];
            *(float4*)&a[4] = *(const float4*)&As[k][ty * 8 + 4];
            *(float4*)&b[0] = *(const float4*)&Bs[k][tx * 8 + 0];
            *(float4*)&b[4] = *(const float4*)&Bs[k][tx * 8 + 4];
#pragma unroll
            for (int i = 0; i < 8; i++)
#pragma unroll
                for (int j = 0; j < 8; j++)
                    acc[i][j] += a[i] * b[j];
        }
    }
    float bj[8];
#pragma unroll
    for (int j = 0; j < 8; j++) {
        int n = n0 + tx * 8 + j;
        bj[j] = bih[n] + bhh[n];
    }
#pragma unroll
    for (int i = 0; i < 8; i++) {
        float4 v0, v1;
        v0.x = acc[i][0] + bj[0]; v0.y = acc[i][1] + bj[1];
        v0.z = acc[i][2] + bj[2]; v0.w = acc[i][3] + bj[3];
        v1.x = acc[i][4] + bj[4]; v1.y = acc[i][5] + bj[5];
        v1.z = acc[i][6] + bj[6]; v1.w = acc[i][7] + bj[7];
        float* cp = C + (size_t)(m0 + ty * 8 + i) * G4 + n0 + tx * 8;
        *(float4*)(cp + 0) = v0;
        *(float4*)(cp + 4) = v1;
    }
}

// ---------------------------------------------------------------------------
// K3/K5: sequential LSTM scan. grid=256 WGs x 256 threads, 1 WG/CU.
// WG w owns h-indices [4w,4w+4) -> 16 gate rows {g*1024 + 4w + s}.
// R5 protocol: ZERO counters. Each h-value travels as one u64
// (round_tag<<32 | f32bits), parity double-buffered. Producers: 4
// fire-and-forget relaxed agent 8B stores. Consumers: retry-load own 4 u64s
// (32B coalesced) until all tags match. Readiness+payload = ONE MALL round
// trip; poll traffic spread over 64 lines (no single hot line -> no queueing
// collapse, which is what capped R2/R4 at 7.2 us/round).
// Parity reuse is safe: WG can only reach round t+2's publish after reading
// all h[t+2], which requires every WG to have consumed h[t+1] already.
// ---------------------------------------------------------------------------
__global__ __launch_bounds__(256, 1) void k_scan(const float* __restrict__ xg,
                                                 const float* __restrict__ Whh,
                                                 float* __restrict__ hbuf,
                                                 u64* slots,   // [2][1024] tagged
                                                 float* __restrict__ out) {
    const int tid = threadIdx.x;
    const int w   = blockIdx.x;
    const int wv  = tid >> 6;             // wave 0..3
    const int ln  = tid & 63;             // lane
    const int rs  = tid >> 4;             // row 0..15 (g = rs>>2, s = rs&3)
    const int ck  = tid & 15;             // k-chunk of 64
    const int g   = rs >> 2, s = rs & 3;
    const int r   = g * DM + w * 4 + s;   // global gate row

    __shared__ float wlds[4 * 4096];      // 64 KB weights, [wave][e][lane*4]
    __shared__ float hl[16 * 68];         // h staged, chunk stride 68
    __shared__ float gp[16];              // gate preactivations

    // ---- prologue: weights -> LDS (self-storage; lane-contiguous) ----
    {
        const float4* gw = (const float4*)(Whh + (size_t)r * DM + ck * 64);
#pragma unroll
        for (int e = 0; e < 16; e++) {
            float4 v = gw[e];
            *(float4*)&wlds[wv * 4096 + e * 256 + ln * 4] = v;
        }
    }
    __syncthreads();

    const int stc = tid >> 4;             // stage chunk for h[tid*4..+4)
    const int sto = (tid & 15) * 4;
    float c_state = 0.0f, h_last = 0.0f;

    for (int t = 0; t < T_SEQ; t++) {
        // prefetch this round's input preactivation (one per gate row)
        float xgv = 0.0f;
        if (ck == 0) xgv = xg[(size_t)t * G4 + r];

        if (t == 0) {
            float4 z; z.x = z.y = z.z = z.w = 0.0f;
            *(float4*)&hl[stc * 68 + sto] = z;
        } else {
            // tagged payload: retry until all 4 own slots carry tag==t
            const u64* sp = slots + (size_t)(t & 1) * 1024 + tid * 4;
            const u32 want = (u32)t;
            u64 a0, a1, a2, a3;
            for (;;) {
                a0 = __hip_atomic_load(sp + 0, __ATOMIC_RELAXED, __HIP_MEMORY_SCOPE_AGENT);
                a1 = __hip_atomic_load(sp + 1, __ATOMIC_RELAXED, __HIP_MEMORY_SCOPE_AGENT);
                a2 = __hip_atomic_load(sp + 2, __ATOMIC_RELAXED, __HIP_MEMORY_SCOPE_AGENT);
                a3 = __hip_atomic_load(sp + 3, __ATOMIC_RELAXED, __HIP_MEMORY_SCOPE_AGENT);
                bool ok = ((u32)(a0 >> 32) == want) & ((u32)(a1 >> 32) == want) &
                          ((u32)(a2 >> 32) == want) & ((u32)(a3 >> 32) == want);
                if (ok) break;
            }
            float4 hv;
            hv.x = __uint_as_float((u32)a0); hv.y = __uint_as_float((u32)a1);
            hv.z = __uint_as_float((u32)a2); hv.w = __uint_as_float((u32)a3);
            *(float4*)&hl[stc * 68 + sto] = hv;
        }
        __syncthreads();

        // ---- dot: row r, k-chunk [ck*64, +64), weights from LDS ----
        const float* wp = &wlds[wv * 4096 + ln * 4];
        const float* hp = &hl[ck * 68];
        float a0 = 0.f, a1 = 0.f, a2 = 0.f, a3 = 0.f;
#pragma unroll
        for (int e = 0; e < 16; e++) {
            float4 wv4 = *(const float4*)&wp[e * 256];
            float4 hv4 = *(const float4*)&hp[e * 4];
            a0 += wv4.x * hv4.x;
            a1 += wv4.y * hv4.y;
            a2 += wv4.z * hv4.z;
            a3 += wv4.w * hv4.w;
        }
        float acc = (a0 + a1) + (a2 + a3);
        acc += __shfl_xor(acc, 1, 16);
        acc += __shfl_xor(acc, 2, 16);
        acc += __shfl_xor(acc, 4, 16);
        acc += __shfl_xor(acc, 8, 16);
        if (ck == 0) gp[rs] = xgv + acc;
        __syncthreads();

        // ---- gate math + publish (tag travels WITH the data; no fence,
        //      no counter, fire-and-forget) ----
        if (tid < 4) {
            float i_ = gp[0 + tid];
            float f_ = gp[4 + tid];
            float g_ = gp[8 + tid];
            float o_ = gp[12 + tid];
            c_state = sigmoidf_(f_) * c_state + sigmoidf_(i_) * tanhf_(g_);
            float h = sigmoidf_(o_) * tanhf_(c_state);
            h_last = h;
            hbuf[(size_t)(t + 1) * DM + w * 4 + tid] = h;   // history (for GEMM)
            u64 v = ((u64)(u32)(t + 1) << 32) | (u64)__float_as_uint(h);
            __hip_atomic_store(slots + (size_t)((t + 1) & 1) * 1024 + w * 4 + tid,
                               v, __ATOMIC_RELAXED, __HIP_MEMORY_SCOPE_AGENT);
        }
        // no extra barrier: next round's hl writes are behind the staging
        // barrier; gp reads of this round finish before writers re-reach it.
    }

    if (out != nullptr && tid < 4) {
        out[w * 4 + tid] = lrelu_(h_last);
    }
}

// ---------------------------------------------------------------------------
extern "C" void kernel_launch(void* const* d_in, const int* in_sizes, int n_in,
                              void* d_out, int out_size, void* d_ws, size_t ws_size,
                              hipStream_t stream) {
    const float* inp = (const float*)d_in[0];   // 4096 x 64
    const float* W1  = (const float*)d_in[1];   // 1024 x 64
    const float* b1  = (const float*)d_in[2];   // 1024
    const float* Wih = (const float*)d_in[3];   // 2 x 4096 x 1024
    const float* Whh = (const float*)d_in[4];   // 2 x 4096 x 1024
    const float* bih = (const float*)d_in[5];   // 2 x 4096
    const float* bhh = (const float*)d_in[6];   // 2 x 4096
    float* out = (float*)d_out;                 // 1024

    // workspace layout (fp32 elements unless noted)
    float* x   = (float*)d_ws;                          // 4096*1024
    float* xg  = x + (size_t)T_SEQ * DM;                // 4096*4096
    float* hb1 = xg + (size_t)T_SEQ * G4;               // 4097*1024
    float* hb2 = hb1 + (size_t)(T_SEQ + 1) * DM;        // 4097*1024
    u64*   sl0 = (u64*)(hb2 + (size_t)(T_SEQ + 1) * DM);   // 2*1024 u64
    u64*   sl1 = sl0 + 2048;                               // 2*1024 u64
    (void)in_sizes; (void)n_in; (void)out_size; (void)ws_size;

    // Phase 1: input projection
    k_input<<<dim3(T_SEQ), dim3(256), 0, stream>>>(inp, W1, b1, x);

    // Phase 2: xg = x @ Wih0^T + (bih0+bhh0)
    k_gemm<<<dim3(32, 32), dim3(256), 0, stream>>>(x, Wih, bih, bhh, xg);

    // Phase 3: layer-0 scan (writes hb1[1..T])
    k_scan<<<dim3(256), dim3(256), 0, stream>>>(xg, Whh, hb1, sl0, nullptr);

    // Phase 4: xg = hs1 @ Wih1^T + (bih1+bhh1)
    k_gemm<<<dim3(32, 32), dim3(256), 0, stream>>>(hb1 + DM, Wih + LSTRIDE_W,
                                                   bih + LSTRIDE_B, bhh + LSTRIDE_B, xg);

    // Phase 5: layer-1 scan, final h -> leaky_relu -> out
    k_scan<<<dim3(256), dim3(256), 0, stream>>>(xg, Whh + LSTRIDE_W, hb2, sl1, out);
}

// Round 7
// 22379.095 us; speedup vs baseline: 3.9893x; 1.2399x over previous
//
#include <hip/hip_runtime.h>
#include <hip/hip_fp16.h>
#include <math.h>

// Problem dims (fixed)
#define T_SEQ 4096
#define DIN   64
#define DM    1024
#define G4    4096              // 4*DM gate rows
#define LSTRIDE_W ((size_t)G4 * DM)   // per-layer Wih/Whh stride
#define LSTRIDE_B ((size_t)G4)        // per-layer bias stride

typedef unsigned long long u64;
typedef unsigned int u32;

__device__ __forceinline__ float sigmoidf_(float x) {
    return 1.0f / (1.0f + __expf(-x));
}
__device__ __forceinline__ float tanhf_(float x) {
    float ax = fabsf(x);
    float e  = __expf(-2.0f * ax);
    float t  = (1.0f - e) / (1.0f + e);
    return copysignf(t, x);
}
__device__ __forceinline__ float lrelu_(float x) {
    return x > 0.0f ? x : 0.01f * x;
}

// pack two fp32 -> one u32 of two f16 (v_cvt_pkrtz_f16_f32)
__device__ __forceinline__ u32 pk2_(float x, float y) {
    typedef __fp16 hv2 __attribute__((ext_vector_type(2)));
    union { hv2 h; u32 u; } c;
    c.h = __builtin_amdgcn_cvt_pkrtz(x, y);
    return c.u;
}
// dot of two f16-pairs (converted to fp32; v_cvt_f32_f16 is full-rate)
__device__ __forceinline__ float d2_(u32 a, u32 b) {
    union { u32 u; __half2 h; } ua, ub;
    ua.u = a; ub.u = b;
    float2 fa = __half22float2(ua.h);
    float2 fb = __half22float2(ub.h);
    return fa.x * fb.x + fa.y * fb.y;
}
__device__ __forceinline__ float dot8_(uint4 q, uint4 h, float acc) {
    return acc + d2_(q.x, h.x) + d2_(q.y, h.y) + d2_(q.z, h.z) + d2_(q.w, h.w);
}

// ---------------------------------------------------------------------------
// K1: x[t,d] = leaky_relu(sum_k inp[t,k]*W1[d,k] + b1[d]);  grid=4096, block=256
// ---------------------------------------------------------------------------
__global__ __launch_bounds__(256) void k_input(const float* __restrict__ inp,
                                               const float* __restrict__ W1,
                                               const float* __restrict__ b1,
                                               float* __restrict__ x) {
    __shared__ float s_in[DIN];
    const int t   = blockIdx.x;
    const int tid = threadIdx.x;
    if (tid < DIN) s_in[tid] = inp[(size_t)t * DIN + tid];
    __syncthreads();
#pragma unroll
    for (int q = 0; q < 4; q++) {
        const int d = tid + q * 256;
        const float4* wr = (const float4*)(W1 + (size_t)d * DIN);
        float acc = 0.0f;
#pragma unroll
        for (int e = 0; e < 16; e++) {
            float4 w = wr[e];
            acc += w.x * s_in[e * 4 + 0] + w.y * s_in[e * 4 + 1] +
                   w.z * s_in[e * 4 + 2] + w.w * s_in[e * 4 + 3];
        }
        acc += b1[d];
        x[(size_t)t * DM + d] = lrelu_(acc);
    }
}

// ---------------------------------------------------------------------------
// K2: xg[m,n] = sum_k x[m,k]*Wih0[n,k] + (bih0[n]+bhh0[n])
// 128x128 tile, BK=16, 256 threads, 8x8 per thread.
// ---------------------------------------------------------------------------
__global__ __launch_bounds__(256) void k_gemm(const float* __restrict__ A,
                                              const float* __restrict__ B,
                                              const float* __restrict__ bih,
                                              const float* __restrict__ bhh,
                                              float* __restrict__ C) {
    const int K = DM;
    __shared__ float As[16][132];
    __shared__ float Bs[16][132];
    const int tid = threadIdx.x;
    const int m0 = blockIdx.y * 128, n0 = blockIdx.x * 128;
    const int tx = tid & 15, ty = tid >> 4;
    const int lr = tid >> 1;
    const int lc = (tid & 1) * 8;

    float acc[8][8] = {};
    const float4* ag = (const float4*)(A + (size_t)(m0 + lr) * K + lc);
    const float4* bg = (const float4*)(B + (size_t)(n0 + lr) * K + lc);

    for (int k0 = 0; k0 < K; k0 += 16) {
        float4 a0 = ag[0], a1 = ag[1];
        float4 b0 = bg[0], b1v = bg[1];
        ag += 4; bg += 4;
        __syncthreads();
        As[lc + 0][lr] = a0.x; As[lc + 1][lr] = a0.y; As[lc + 2][lr] = a0.z; As[lc + 3][lr] = a0.w;
        As[lc + 4][lr] = a1.x; As[lc + 5][lr] = a1.y; As[lc + 6][lr] = a1.z; As[lc + 7][lr] = a1.w;
        Bs[lc + 0][lr] = b0.x; Bs[lc + 1][lr] = b0.y; Bs[lc + 2][lr] = b0.z; Bs[lc + 3][lr] = b0.w;
        Bs[lc + 4][lr] = b1v.x; Bs[lc + 5][lr] = b1v.y; Bs[lc + 6][lr] = b1v.z; Bs[lc + 7][lr] = b1v.w;
        __syncthreads();
#pragma unroll
        for (int k = 0; k < 16; k++) {
            float a[8], b[8];
            *(float4*)&a[0] = *(const float4*)&As[k][ty * 8 + 0];
            *(float4*)&a[4] = *(const float4*)&As[k][ty * 8 + 4];
            *(float4*)&b[0] = *(const float4*)&Bs[k][tx * 8 + 0];
            *(float4*)&b[4] = *(const float4*)&Bs[k][tx * 8 + 4];
#pragma unroll
            for (int i = 0; i < 8; i++)
#pragma unroll
                for (int j = 0; j < 8; j++)
                    acc[i][j] += a[i] * b[j];
        }
    }
    float bj[8];
#pragma unroll
    for (int j = 0; j < 8; j++) {
        int n = n0 + tx * 8 + j;
        bj[j] = bih[n] + bhh[n];
    }
#pragma unroll
    for (int i = 0; i < 8; i++) {
        float4 v0, v1;
        v0.x = acc[i][0] + bj[0]; v0.y = acc[i][1] + bj[1];
        v0.z = acc[i][2] + bj[2]; v0.w = acc[i][3] + bj[3];
        v1.x = acc[i][4] + bj[4]; v1.y = acc[i][5] + bj[5];
        v1.z = acc[i][6] + bj[6]; v1.w = acc[i][7] + bj[7];
        float* cp = C + (size_t)(m0 + ty * 8 + i) * G4 + n0 + tx * 8;
        *(float4*)(cp + 0) = v0;
        *(float4*)(cp + 4) = v1;
    }
}

// ---------------------------------------------------------------------------
// K3: fused 2-layer pipelined scan. grid=256 WGs x 256 threads, 1 WG/CU.
// Round t (0..T): uses h0[t-1], h1[t-2] (staged) to compute
//   gp0 = Whh0·h0[t-1]  -> h0[t]        (needs xg[t])
//   gp1 = Wih1·h0[t-1]  =  x1[t-1]
//   gp2 = Whh1·h1[t-2]  -> h1[t-1] = gates(gp1+gp2+b1)
// Publishes h0[t] and h1[t-1] with tag t+1 (R5 tagged-u64 protocol, parity
// double-buffer, fire-and-forget relaxed agent stores, no counters).
// Weights: f16 in LDS (3 matrices x 16 rows x 1024 = 96 KB), self-storage
// layout [m][wave][e][lane] -> conflict-free ds_read_b128. h staged as f16.
// fp32 math after v_cvt_f32_f16; f16 weight error ~2^-10 -> h err ~5e-4,
// well under the 6.8e-3 threshold (watch absmax in the bench).
// Rounds: 4097 instead of 2x4096; phase-4 GEMM + h-history writes eliminated.
// ---------------------------------------------------------------------------
__global__ __launch_bounds__(256, 1) void k_scan2(
        const float* __restrict__ xg,     // T x 4096 layer-0 preacts
        const float* __restrict__ Wih1,
        const float* __restrict__ Whh0,
        const float* __restrict__ Whh1,
        const float* __restrict__ bih1,
        const float* __restrict__ bhh1,
        u64* sl0,                         // [2][1024] tagged h0 slots
        u64* sl1,                         // [2][1024] tagged h1 slots
        float* __restrict__ out) {
    const int tid = threadIdx.x;
    const int w   = blockIdx.x;
    const int wv  = tid >> 6;             // wave 0..3
    const int ln  = tid & 63;             // lane
    const int rs  = tid >> 4;             // row slot 0..15 (g=rs>>2, s=rs&3)
    const int ck  = tid & 15;             // k-chunk of 64
    const int g   = rs >> 2, s = rs & 3;
    const int r   = g * DM + w * 4 + s;   // global gate row (same for all 3 mats)

    __shared__ uint4 wlds[3][4][8][64];   // 96 KB f16 weights
    __shared__ uint4 hst[2][16][9];       // staged h0/h1 as f16, 144B chunk rows
    __shared__ float gp0[16], gp1[16], gp2[16];

    // ---- prologue: pack f16 weights into LDS (self-storage) ----
    {
        const float* srcs[3] = { Whh0, Wih1, Whh1 };
#pragma unroll
        for (int m = 0; m < 3; m++) {
            const float4* gw = (const float4*)(srcs[m] + (size_t)r * DM + ck * 64);
#pragma unroll
            for (int e = 0; e < 8; e++) {
                float4 a = gw[e * 2 + 0];
                float4 b = gw[e * 2 + 1];
                uint4 q;
                q.x = pk2_(a.x, a.y); q.y = pk2_(a.z, a.w);
                q.z = pk2_(b.x, b.y); q.w = pk2_(b.z, b.w);
                wlds[m][wv][e][ln] = q;
            }
        }
    }
    // layer-1 gate biases (state threads 4..7; s1 = tid-4)
    float b1s[4] = {0.f, 0.f, 0.f, 0.f};
    if (tid >= 4 && tid < 8) {
        const int s1 = tid - 4;
#pragma unroll
        for (int gg = 0; gg < 4; gg++)
            b1s[gg] = bih1[gg * DM + w * 4 + s1] + bhh1[gg * DM + w * 4 + s1];
    }
    __syncthreads();

    const int stc = tid >> 4;             // stage chunk for h[tid*4..+4)
    const int sto = tid & 15;             // u64 index within chunk row
    float c0 = 0.f, h0v = 0.f, c1 = 0.f, h1v = 0.f;

    for (int t = 0; t <= T_SEQ; t++) {
        // prefetch layer-0 input preactivation (one per gate row)
        float xgv = 0.0f;
        if (ck == 0 && t < T_SEQ) xgv = xg[(size_t)t * G4 + r];

        if (t == 0) {
            ((u64*)&hst[0][stc][0])[sto] = 0ull;
            ((u64*)&hst[1][stc][0])[sto] = 0ull;
        } else {
            // tagged payload: retry until all 8 own slots carry tag==t
            const u64* p0 = sl0 + (size_t)(t & 1) * 1024 + tid * 4;
            const u64* p1 = sl1 + (size_t)(t & 1) * 1024 + tid * 4;
            const u32 want = (u32)t;
            u64 a0, a1, a2, a3, d0, d1, d2, d3;
            for (;;) {
                a0 = __hip_atomic_load(p0 + 0, __ATOMIC_RELAXED, __HIP_MEMORY_SCOPE_AGENT);
                a1 = __hip_atomic_load(p0 + 1, __ATOMIC_RELAXED, __HIP_MEMORY_SCOPE_AGENT);
                a2 = __hip_atomic_load(p0 + 2, __ATOMIC_RELAXED, __HIP_MEMORY_SCOPE_AGENT);
                a3 = __hip_atomic_load(p0 + 3, __ATOMIC_RELAXED, __HIP_MEMORY_SCOPE_AGENT);
                d0 = __hip_atomic_load(p1 + 0, __ATOMIC_RELAXED, __HIP_MEMORY_SCOPE_AGENT);
                d1 = __hip_atomic_load(p1 + 1, __ATOMIC_RELAXED, __HIP_MEMORY_SCOPE_AGENT);
                d2 = __hip_atomic_load(p1 + 2, __ATOMIC_RELAXED, __HIP_MEMORY_SCOPE_AGENT);
                d3 = __hip_atomic_load(p1 + 3, __ATOMIC_RELAXED, __HIP_MEMORY_SCOPE_AGENT);
                bool ok = ((u32)(a0 >> 32) == want) & ((u32)(a1 >> 32) == want) &
                          ((u32)(a2 >> 32) == want) & ((u32)(a3 >> 32) == want) &
                          ((u32)(d0 >> 32) == want) & ((u32)(d1 >> 32) == want) &
                          ((u32)(d2 >> 32) == want) & ((u32)(d3 >> 32) == want);
                if (ok) break;
            }
            u32 p00 = pk2_(__uint_as_float((u32)a0), __uint_as_float((u32)a1));
            u32 p01 = pk2_(__uint_as_float((u32)a2), __uint_as_float((u32)a3));
            u32 p10 = pk2_(__uint_as_float((u32)d0), __uint_as_float((u32)d1));
            u32 p11 = pk2_(__uint_as_float((u32)d2), __uint_as_float((u32)d3));
            ((u64*)&hst[0][stc][0])[sto] = ((u64)p01 << 32) | p00;
            ((u64*)&hst[1][stc][0])[sto] = ((u64)p11 << 32) | p10;
        }
        __syncthreads();

        // ---- three GEMVs: rows r of Whh0/Wih1 (dot h0) and Whh1 (dot h1) ----
        float acc0 = 0.f, acc1 = 0.f, acc2 = 0.f;
#pragma unroll
        for (int e = 0; e < 8; e++) {
            uint4 q0 = wlds[0][wv][e][ln];
            uint4 q1 = wlds[1][wv][e][ln];
            uint4 q2 = wlds[2][wv][e][ln];
            uint4 ha = hst[0][ck][e];
            uint4 hb = hst[1][ck][e];
            acc0 = dot8_(q0, ha, acc0);
            acc1 = dot8_(q1, ha, acc1);
            acc2 = dot8_(q2, hb, acc2);
        }
#pragma unroll
        for (int m = 1; m <= 8; m <<= 1) {
            acc0 += __shfl_xor(acc0, m, 64);
            acc1 += __shfl_xor(acc1, m, 64);
            acc2 += __shfl_xor(acc2, m, 64);
        }
        if (ck == 0) {
            gp0[rs] = xgv + acc0;
            gp1[rs] = acc1;
            gp2[rs] = acc2;
        }
        __syncthreads();

        // ---- gate math + publish (wave 0; fire-and-forget tagged stores) ----
        if (tid < 4) {
            if (t < T_SEQ) {
                float pi = gp0[0 + tid];
                float pf = gp0[4 + tid];
                float pg = gp0[8 + tid];
                float po = gp0[12 + tid];
                c0 = sigmoidf_(pf) * c0 + sigmoidf_(pi) * tanhf_(pg);
                h0v = sigmoidf_(po) * tanhf_(c0);
                u64 v = ((u64)(u32)(t + 1) << 32) | (u64)__float_as_uint(h0v);
                __hip_atomic_store(sl0 + (size_t)((t + 1) & 1) * 1024 + w * 4 + tid,
                                   v, __ATOMIC_RELAXED, __HIP_MEMORY_SCOPE_AGENT);
            }
        } else if (tid < 8) {
            const int s1 = tid - 4;
            if (t > 0) {
                float pi = gp1[0 + s1]  + gp2[0 + s1]  + b1s[0];
                float pf = gp1[4 + s1]  + gp2[4 + s1]  + b1s[1];
                float pg = gp1[8 + s1]  + gp2[8 + s1]  + b1s[2];
                float po = gp1[12 + s1] + gp2[12 + s1] + b1s[3];
                c1 = sigmoidf_(pf) * c1 + sigmoidf_(pi) * tanhf_(pg);
                h1v = sigmoidf_(po) * tanhf_(c1);
            }
            if (t < T_SEQ) {
                u64 v = ((u64)(u32)(t + 1) << 32) | (u64)__float_as_uint(h1v);
                __hip_atomic_store(sl1 + (size_t)((t + 1) & 1) * 1024 + w * 4 + s1,
                                   v, __ATOMIC_RELAXED, __HIP_MEMORY_SCOPE_AGENT);
            }
        }
        // hazards: round-t hst reads are separated from round-t+1 hst writes
        // by the reduce barrier; gp reads precede the next staging barrier.
    }

    if (tid >= 4 && tid < 8) {
        out[w * 4 + (tid - 4)] = lrelu_(h1v);   // h1[T-1]
    }
}

// ---------------------------------------------------------------------------
extern "C" void kernel_launch(void* const* d_in, const int* in_sizes, int n_in,
                              void* d_out, int out_size, void* d_ws, size_t ws_size,
                              hipStream_t stream) {
    const float* inp = (const float*)d_in[0];   // 4096 x 64
    const float* W1  = (const float*)d_in[1];   // 1024 x 64
    const float* b1  = (const float*)d_in[2];   // 1024
    const float* Wih = (const float*)d_in[3];   // 2 x 4096 x 1024
    const float* Whh = (const float*)d_in[4];   // 2 x 4096 x 1024
    const float* bih = (const float*)d_in[5];   // 2 x 4096
    const float* bhh = (const float*)d_in[6];   // 2 x 4096
    float* out = (float*)d_out;                 // 1024

    // workspace layout
    float* x   = (float*)d_ws;                          // 4096*1024 f32
    float* xg  = x + (size_t)T_SEQ * DM;                // 4096*4096 f32
    u64*   sl0 = (u64*)(xg + (size_t)T_SEQ * G4);       // 2*1024 u64
    u64*   sl1 = sl0 + 2048;                            // 2*1024 u64
    (void)in_sizes; (void)n_in; (void)out_size; (void)ws_size;

    // Phase 1: input projection
    k_input<<<dim3(T_SEQ), dim3(256), 0, stream>>>(inp, W1, b1, x);

    // Phase 2: xg = x @ Wih0^T + (bih0+bhh0)
    k_gemm<<<dim3(32, 32), dim3(256), 0, stream>>>(x, Wih, bih, bhh, xg);

    // Phase 3: fused 2-layer pipelined scan (tag-in-payload, no counters)
    k_scan2<<<dim3(256), dim3(256), 0, stream>>>(
        xg, Wih + LSTRIDE_W, Whh, Whh + LSTRIDE_W,
        bih + LSTRIDE_B, bhh + LSTRIDE_B, sl0, sl1, out);
}

// Round 8
// 13063.544 us; speedup vs baseline: 6.8341x; 1.7131x over previous
//
#include <hip/hip_runtime.h>
#include <hip/hip_fp16.h>
#include <math.h>

// Problem dims (fixed)
#define T_SEQ 4096
#define DIN   64
#define DM    1024
#define G4    4096              // 4*DM gate rows
#define LSTRIDE_W ((size_t)G4 * DM)   // per-layer Wih/Whh stride
#define LSTRIDE_B ((size_t)G4)        // per-layer bias stride

typedef unsigned long long u64;
typedef unsigned int u32;

__device__ __forceinline__ float sigmoidf_(float x) {
    return 1.0f / (1.0f + __expf(-x));
}
__device__ __forceinline__ float tanhf_(float x) {
    float ax = fabsf(x);
    float e  = __expf(-2.0f * ax);
    float t  = (1.0f - e) / (1.0f + e);
    return copysignf(t, x);
}
__device__ __forceinline__ float lrelu_(float x) {
    return x > 0.0f ? x : 0.01f * x;
}

// pack two fp32 -> one u32 of two f16 (v_cvt_pkrtz_f16_f32)
__device__ __forceinline__ u32 pk2_(float x, float y) {
    typedef __fp16 hv2 __attribute__((ext_vector_type(2)));
    union { hv2 h; u32 u; } c;
    c.h = __builtin_amdgcn_cvt_pkrtz(x, y);
    return c.u;
}
// dot of two f16-pairs (converted to fp32; v_cvt_f32_f16 is full-rate)
__device__ __forceinline__ float d2_(u32 a, u32 b) {
    union { u32 u; __half2 h; } ua, ub;
    ua.u = a; ub.u = b;
    float2 fa = __half22float2(ua.h);
    float2 fb = __half22float2(ub.h);
    return fa.x * fb.x + fa.y * fb.y;
}
__device__ __forceinline__ float dot8_(uint4 q, uint4 h, float acc) {
    return acc + d2_(q.x, h.x) + d2_(q.y, h.y) + d2_(q.z, h.z) + d2_(q.w, h.w);
}

// ---------------------------------------------------------------------------
// K1: x[t,d] = leaky_relu(sum_k inp[t,k]*W1[d,k] + b1[d]);  grid=4096, block=256
// ---------------------------------------------------------------------------
__global__ __launch_bounds__(256) void k_input(const float* __restrict__ inp,
                                               const float* __restrict__ W1,
                                               const float* __restrict__ b1,
                                               float* __restrict__ x) {
    __shared__ float s_in[DIN];
    const int t   = blockIdx.x;
    const int tid = threadIdx.x;
    if (tid < DIN) s_in[tid] = inp[(size_t)t * DIN + tid];
    __syncthreads();
#pragma unroll
    for (int q = 0; q < 4; q++) {
        const int d = tid + q * 256;
        const float4* wr = (const float4*)(W1 + (size_t)d * DIN);
        float acc = 0.0f;
#pragma unroll
        for (int e = 0; e < 16; e++) {
            float4 w = wr[e];
            acc += w.x * s_in[e * 4 + 0] + w.y * s_in[e * 4 + 1] +
                   w.z * s_in[e * 4 + 2] + w.w * s_in[e * 4 + 3];
        }
        acc += b1[d];
        x[(size_t)t * DM + d] = lrelu_(acc);
    }
}

// ---------------------------------------------------------------------------
// K2: xg[m,n] = sum_k x[m,k]*Wih0[n,k] + (bih0[n]+bhh0[n])
// 128x128 tile, BK=16, 256 threads, 8x8 per thread.
// ---------------------------------------------------------------------------
__global__ __launch_bounds__(256) void k_gemm(const float* __restrict__ A,
                                              const float* __restrict__ B,
                                              const float* __restrict__ bih,
                                              const float* __restrict__ bhh,
                                              float* __restrict__ C) {
    const int K = DM;
    __shared__ float As[16][132];
    __shared__ float Bs[16][132];
    const int tid = threadIdx.x;
    const int m0 = blockIdx.y * 128, n0 = blockIdx.x * 128;
    const int tx = tid & 15, ty = tid >> 4;
    const int lr = tid >> 1;
    const int lc = (tid & 1) * 8;

    float acc[8][8] = {};
    const float4* ag = (const float4*)(A + (size_t)(m0 + lr) * K + lc);
    const float4* bg = (const float4*)(B + (size_t)(n0 + lr) * K + lc);

    for (int k0 = 0; k0 < K; k0 += 16) {
        float4 a0 = ag[0], a1 = ag[1];
        float4 b0 = bg[0], b1v = bg[1];
        ag += 4; bg += 4;
        __syncthreads();
        As[lc + 0][lr] = a0.x; As[lc + 1][lr] = a0.y; As[lc + 2][lr] = a0.z; As[lc + 3][lr] = a0.w;
        As[lc + 4][lr] = a1.x; As[lc + 5][lr] = a1.y; As[lc + 6][lr] = a1.z; As[lc + 7][lr] = a1.w;
        Bs[lc + 0][lr] = b0.x; Bs[lc + 1][lr] = b0.y; Bs[lc + 2][lr] = b0.z; Bs[lc + 3][lr] = b0.w;
        Bs[lc + 4][lr] = b1v.x; Bs[lc + 5][lr] = b1v.y; Bs[lc + 6][lr] = b1v.z; Bs[lc + 7][lr] = b1v.w;
        __syncthreads();
#pragma unroll
        for (int k = 0; k < 16; k++) {
            float a[8], b[8];
            *(float4*)&a[0] = *(const float4*)&As[k][ty * 8 + 0];
            *(float4*)&a[4] = *(const float4*)&As[k][ty * 8 + 4];
            *(float4*)&b[0] = *(const float4*)&Bs[k][tx * 8 + 0];
            *(float4*)&b[4] = *(const float4*)&Bs[k][tx * 8 + 4];
#pragma unroll
            for (int i = 0; i < 8; i++)
#pragma unroll
                for (int j = 0; j < 8; j++)
                    acc[i][j] += a[i] * b[j];
        }
    }
    float bj[8];
#pragma unroll
    for (int j = 0; j < 8; j++) {
        int n = n0 + tx * 8 + j;
        bj[j] = bih[n] + bhh[n];
    }
#pragma unroll
    for (int i = 0; i < 8; i++) {
        float4 v0, v1;
        v0.x = acc[i][0] + bj[0]; v0.y = acc[i][1] + bj[1];
        v0.z = acc[i][2] + bj[2]; v0.w = acc[i][3] + bj[3];
        v1.x = acc[i][4] + bj[4]; v1.y = acc[i][5] + bj[5];
        v1.z = acc[i][6] + bj[6]; v1.w = acc[i][7] + bj[7];
        float* cp = C + (size_t)(m0 + ty * 8 + i) * G4 + n0 + tx * 8;
        *(float4*)(cp + 0) = v0;
        *(float4*)(cp + 4) = v1;
    }
}

// ---------------------------------------------------------------------------
// K3: fused 2-layer pipelined scan, CRITICAL-PATH-SPLIT (R8).
// grid=256 WGs x 256 threads, 1 WG/CU. WG w owns h-indices [4w,4w+4).
// Round t: Phase A (critical): poll h0[t-1] -> dot0=Whh0·h0 -> gate ->
//          publish h0[t] tag t+1.  Only this chain is globally serial.
//          Phase B (shadow): poll h1[t-2] (long-visible) -> dot1=Wih1·h0,
//          dot2=Whh1·h1 -> gate -> publish h1[t-1] tag t+1.  Consumed only
//          in the NEXT round's phase B -> a full phase-A of slack.
// Protocol: R5 tagged-u64 slots, parity double-buffer, relaxed agent
// atomics, no counters.  hst/gp parity-double-buffered (4-barrier skeleton).
// Weights f16 in LDS (96 KB) as in R7.
// ---------------------------------------------------------------------------
__global__ __launch_bounds__(256, 1) void k_scan2(
        const float* __restrict__ xg,     // T x 4096 layer-0 preacts
        const float* __restrict__ Wih1,
        const float* __restrict__ Whh0,
        const float* __restrict__ Whh1,
        const float* __restrict__ bih1,
        const float* __restrict__ bhh1,
        u64* sl0,                         // [2][1024] tagged h0 slots
        u64* sl1,                         // [2][1024] tagged h1 slots
        float* __restrict__ out) {
    const int tid = threadIdx.x;
    const int w   = blockIdx.x;
    const int wv  = tid >> 6;             // wave 0..3
    const int ln  = tid & 63;             // lane
    const int rs  = tid >> 4;             // row slot 0..15 (g=rs>>2, s=rs&3)
    const int ck  = tid & 15;             // k-chunk of 64
    const int g   = rs >> 2, s = rs & 3;
    const int r   = g * DM + w * 4 + s;   // global gate row (same for all 3 mats)

    __shared__ uint4 wlds[3][4][8][64];   // 96 KB f16 weights
    __shared__ uint4 hst0[2][16][9];      // h0 staged (f16), parity dbuf
    __shared__ uint4 hst1[2][16][9];      // h1 staged (f16), parity dbuf
    __shared__ float gp0[2][16], gp1[2][16], gp2[2][16];

    // ---- prologue: pack f16 weights into LDS (self-storage) ----
    {
        const float* srcs[3] = { Whh0, Wih1, Whh1 };
#pragma unroll
        for (int m = 0; m < 3; m++) {
            const float4* gw = (const float4*)(srcs[m] + (size_t)r * DM + ck * 64);
#pragma unroll
            for (int e = 0; e < 8; e++) {
                float4 a = gw[e * 2 + 0];
                float4 b = gw[e * 2 + 1];
                uint4 q;
                q.x = pk2_(a.x, a.y); q.y = pk2_(a.z, a.w);
                q.z = pk2_(b.x, b.y); q.w = pk2_(b.z, b.w);
                wlds[m][wv][e][ln] = q;
            }
        }
    }
    // layer-1 gate biases (state threads 4..7; s1 = tid-4)
    float b1s[4] = {0.f, 0.f, 0.f, 0.f};
    if (tid >= 4 && tid < 8) {
        const int s1 = tid - 4;
#pragma unroll
        for (int gg = 0; gg < 4; gg++)
            b1s[gg] = bih1[gg * DM + w * 4 + s1] + bhh1[gg * DM + w * 4 + s1];
    }
    __syncthreads();

    const int stc = tid >> 4;             // stage chunk for h[tid*4..+4)
    const int sto = tid & 15;             // u64 index within chunk row
    float c0 = 0.f, h0v = 0.f, c1 = 0.f, h1v = 0.f;

    for (int t = 0; t <= T_SEQ; t++) {
        const int par = t & 1;
        // prefetch layer-0 input preactivation (one per gate row)
        float xgv = 0.0f;
        if (ck == 0 && t < T_SEQ) xgv = xg[(size_t)t * G4 + r];

        // ================= Phase A: critical h0 chain =================
        if (t == 0) {
            ((u64*)&hst0[0][stc][0])[sto] = 0ull;
        } else {
            // poll ONLY sl0: 4 loads per retry generation
            const u64* p0 = sl0 + (size_t)par * 1024 + tid * 4;
            const u32 want = (u32)t;
            u64 a0, a1, a2, a3;
            for (;;) {
                a0 = __hip_atomic_load(p0 + 0, __ATOMIC_RELAXED, __HIP_MEMORY_SCOPE_AGENT);
                a1 = __hip_atomic_load(p0 + 1, __ATOMIC_RELAXED, __HIP_MEMORY_SCOPE_AGENT);
                a2 = __hip_atomic_load(p0 + 2, __ATOMIC_RELAXED, __HIP_MEMORY_SCOPE_AGENT);
                a3 = __hip_atomic_load(p0 + 3, __ATOMIC_RELAXED, __HIP_MEMORY_SCOPE_AGENT);
                bool ok = ((u32)(a0 >> 32) == want) & ((u32)(a1 >> 32) == want) &
                          ((u32)(a2 >> 32) == want) & ((u32)(a3 >> 32) == want);
                if (ok) break;
            }
            u32 p00 = pk2_(__uint_as_float((u32)a0), __uint_as_float((u32)a1));
            u32 p01 = pk2_(__uint_as_float((u32)a2), __uint_as_float((u32)a3));
            ((u64*)&hst0[par][stc][0])[sto] = ((u64)p01 << 32) | p00;
        }
        __syncthreads();   // B1: hst0[par] visible

        // dot0: Whh0 row r · h0[t-1]
        float acc0 = 0.f;
#pragma unroll
        for (int e = 0; e < 8; e++) {
            acc0 = dot8_(wlds[0][wv][e][ln], hst0[par][ck][e], acc0);
        }
#pragma unroll
        for (int m = 1; m <= 8; m <<= 1) acc0 += __shfl_xor(acc0, m, 64);
        if (ck == 0) gp0[par][rs] = xgv + acc0;
        __syncthreads();   // B2: gp0 visible

        if (tid < 4 && t < T_SEQ) {
            float pi = gp0[par][0 + tid];
            float pf = gp0[par][4 + tid];
            float pg = gp0[par][8 + tid];
            float po = gp0[par][12 + tid];
            c0 = sigmoidf_(pf) * c0 + sigmoidf_(pi) * tanhf_(pg);
            h0v = sigmoidf_(po) * tanhf_(c0);
            u64 v = ((u64)(u32)(t + 1) << 32) | (u64)__float_as_uint(h0v);
            __hip_atomic_store(sl0 + (size_t)((t + 1) & 1) * 1024 + w * 4 + tid,
                               v, __ATOMIC_RELAXED, __HIP_MEMORY_SCOPE_AGENT);
        }

        // ================= Phase B: shadow h1 work =================
        if (t == 0) {
            ((u64*)&hst1[0][stc][0])[sto] = 0ull;
        } else {
            // h1[t-2] was published a full round ago -> ~1 generation
            const u64* p1 = sl1 + (size_t)par * 1024 + tid * 4;
            const u32 want = (u32)t;
            u64 d0, d1, d2, d3;
            for (;;) {
                d0 = __hip_atomic_load(p1 + 0, __ATOMIC_RELAXED, __HIP_MEMORY_SCOPE_AGENT);
                d1 = __hip_atomic_load(p1 + 1, __ATOMIC_RELAXED, __HIP_MEMORY_SCOPE_AGENT);
                d2 = __hip_atomic_load(p1 + 2, __ATOMIC_RELAXED, __HIP_MEMORY_SCOPE_AGENT);
                d3 = __hip_atomic_load(p1 + 3, __ATOMIC_RELAXED, __HIP_MEMORY_SCOPE_AGENT);
                bool ok = ((u32)(d0 >> 32) == want) & ((u32)(d1 >> 32) == want) &
                          ((u32)(d2 >> 32) == want) & ((u32)(d3 >> 32) == want);
                if (ok) break;
            }
            u32 p10 = pk2_(__uint_as_float((u32)d0), __uint_as_float((u32)d1));
            u32 p11 = pk2_(__uint_as_float((u32)d2), __uint_as_float((u32)d3));
            ((u64*)&hst1[par][stc][0])[sto] = ((u64)p11 << 32) | p10;
        }
        __syncthreads();   // B3: hst1[par] visible

        // dot1: Wih1 row r · h0[t-1];  dot2: Whh1 row r · h1[t-2]
        float acc1 = 0.f, acc2 = 0.f;
#pragma unroll
        for (int e = 0; e < 8; e++) {
            acc1 = dot8_(wlds[1][wv][e][ln], hst0[par][ck][e], acc1);
            acc2 = dot8_(wlds[2][wv][e][ln], hst1[par][ck][e], acc2);
        }
#pragma unroll
        for (int m = 1; m <= 8; m <<= 1) {
            acc1 += __shfl_xor(acc1, m, 64);
            acc2 += __shfl_xor(acc2, m, 64);
        }
        if (ck == 0) { gp1[par][rs] = acc1; gp2[par][rs] = acc2; }
        __syncthreads();   // B4: gp1/gp2 visible

        if (tid >= 4 && tid < 8) {
            const int s1 = tid - 4;
            if (t > 0) {
                float pi = gp1[par][0 + s1]  + gp2[par][0 + s1]  + b1s[0];
                float pf = gp1[par][4 + s1]  + gp2[par][4 + s1]  + b1s[1];
                float pg = gp1[par][8 + s1]  + gp2[par][8 + s1]  + b1s[2];
                float po = gp1[par][12 + s1] + gp2[par][12 + s1] + b1s[3];
                c1 = sigmoidf_(pf) * c1 + sigmoidf_(pi) * tanhf_(pg);
                h1v = sigmoidf_(po) * tanhf_(c1);
            }
            if (t < T_SEQ) {
                u64 v = ((u64)(u32)(t + 1) << 32) | (u64)__float_as_uint(h1v);
                __hip_atomic_store(sl1 + (size_t)((t + 1) & 1) * 1024 + w * 4 + s1,
                                   v, __ATOMIC_RELAXED, __HIP_MEMORY_SCOPE_AGENT);
            }
        }
        // parity double-buffers + B1..B4 separate all LDS read/write pairs.
    }

    if (tid >= 4 && tid < 8) {
        out[w * 4 + (tid - 4)] = lrelu_(h1v);   // h1[T-1]
    }
}

// ---------------------------------------------------------------------------
extern "C" void kernel_launch(void* const* d_in, const int* in_sizes, int n_in,
                              void* d_out, int out_size, void* d_ws, size_t ws_size,
                              hipStream_t stream) {
    const float* inp = (const float*)d_in[0];   // 4096 x 64
    const float* W1  = (const float*)d_in[1];   // 1024 x 64
    const float* b1  = (const float*)d_in[2];   // 1024
    const float* Wih = (const float*)d_in[3];   // 2 x 4096 x 1024
    const float* Whh = (const float*)d_in[4];   // 2 x 4096 x 1024
    const float* bih = (const float*)d_in[5];   // 2 x 4096
    const float* bhh = (const float*)d_in[6];   // 2 x 4096
    float* out = (float*)d_out;                 // 1024

    // workspace layout
    float* x   = (float*)d_ws;                          // 4096*1024 f32
    float* xg  = x + (size_t)T_SEQ * DM;                // 4096*4096 f32
    u64*   sl0 = (u64*)(xg + (size_t)T_SEQ * G4);       // 2*1024 u64
    u64*   sl1 = sl0 + 2048;                            // 2*1024 u64
    (void)in_sizes; (void)n_in; (void)out_size; (void)ws_size;

    // Phase 1: input projection
    k_input<<<dim3(T_SEQ), dim3(256), 0, stream>>>(inp, W1, b1, x);

    // Phase 2: xg = x @ Wih0^T + (bih0+bhh0)
    k_gemm<<<dim3(32, 32), dim3(256), 0, stream>>>(x, Wih, bih, bhh, xg);

    // Phase 3: fused 2-layer pipelined scan (critical-path split)
    k_scan2<<<dim3(256), dim3(256), 0, stream>>>(
        xg, Wih + LSTRIDE_W, Whh, Whh + LSTRIDE_W,
        bih + LSTRIDE_B, bhh + LSTRIDE_B, sl0, sl1, out);
}